// Round 2
// baseline (111.027 us; speedup 1.0000x reference)
//
#include <hip/hip_runtime.h>
#include <stdint.h>

// Problem: x0,y0 [B=64, C=36, L=4096] float32.
// out = y0 * (mean(x0,-1) + mean(y0,-1)), float32.
// Memory-bound: 113.2 MB minimal traffic -> ~18 us roofline at 6.3 TB/s.
//
// Structure: ONE WAVE PER ROW. No LDS, no __syncthreads, no inter-wave
// coupling. Each lane holds its 16 float4 of y in registers, streams x
// with 4 independent accumulators, butterfly-reduces with __shfl_xor
// (all lanes end with the row total), scales and stores.

#define LL     4096
#define ROWS   (64 * 36)        // 2304 rows, one wave each
#define BLOCK  256              // 4 independent waves per block
#define WPB    (BLOCK / 64)     // 4 rows per block
#define NBLK   (ROWS / WPB)     // 576 blocks
#define F4LANE (LL / 4 / 64)    // 16 float4 per lane per row

__global__ __launch_bounds__(BLOCK, 4) void spo2_rowscale(
    const float* __restrict__ x,
    const float* __restrict__ y,
    float* __restrict__ out)
{
    const int wid  = threadIdx.x >> 6;
    const int lane = threadIdx.x & 63;
    const int row  = blockIdx.x * WPB + wid;
    const size_t base = (size_t)row * LL;

    const float4* xv = (const float4*)(x + base);
    const float4* yv = (const float4*)(y + base);
    float4*       ov = (float4*)(out + base);

    // y fully register-held: 16 float4 = 64 VGPR.
    float4 yr[F4LANE];
#pragma unroll
    for (int i = 0; i < F4LANE; ++i)
        yr[i] = yv[lane + i * 64];

    // Stream x with 4 independent partial sums (short dep chains,
    // bounded transient registers).
    float sx0 = 0.f, sx1 = 0.f, sx2 = 0.f, sx3 = 0.f;
#pragma unroll
    for (int i = 0; i < F4LANE; i += 4) {
        float4 a = xv[lane + (i + 0) * 64];
        float4 b = xv[lane + (i + 1) * 64];
        float4 c = xv[lane + (i + 2) * 64];
        float4 d = xv[lane + (i + 3) * 64];
        sx0 += a.x + a.y + a.z + a.w;
        sx1 += b.x + b.y + b.z + b.w;
        sx2 += c.x + c.y + c.z + c.w;
        sx3 += d.x + d.y + d.z + d.w;
    }
    float s = (sx0 + sx1) + (sx2 + sx3);

    // Add y's contribution (already in registers).
    float sy0 = 0.f, sy1 = 0.f;
#pragma unroll
    for (int i = 0; i < F4LANE; i += 2) {
        sy0 += yr[i].x + yr[i].y + yr[i].z + yr[i].w;
        sy1 += yr[i + 1].x + yr[i + 1].y + yr[i + 1].z + yr[i + 1].w;
    }
    s += sy0 + sy1;

    // Wave-64 butterfly: every lane ends with the full row sum.
#pragma unroll
    for (int off = 32; off > 0; off >>= 1)
        s += __shfl_xor(s, off, 64);

    const float scale = s * (1.0f / (float)LL);

#pragma unroll
    for (int i = 0; i < F4LANE; ++i) {
        float4 o;
        o.x = yr[i].x * scale;
        o.y = yr[i].y * scale;
        o.z = yr[i].z * scale;
        o.w = yr[i].w * scale;
        ov[lane + i * 64] = o;
    }
}

extern "C" void kernel_launch(void* const* d_in, const int* in_sizes, int n_in,
                              void* d_out, int out_size, void* d_ws, size_t ws_size,
                              hipStream_t stream) {
    const float* x = (const float*)d_in[0];
    const float* y = (const float*)d_in[1];
    float* out = (float*)d_out;
    spo2_rowscale<<<NBLK, BLOCK, 0, stream>>>(x, y, out);
}

// Round 5
// 108.847 us; speedup vs baseline: 1.0200x; 1.0200x over previous
//
#include <hip/hip_runtime.h>
#include <stdint.h>

// Problem: x0,y0 [B=64, C=36, L=4096] float32.
// out = y0 * (mean(x0,-1) + mean(y0,-1)), float32.
// Memory-bound: 113.2 MB minimal traffic -> ~18 us roofline at 6.3 TB/s.
//
// NOTE (round-2 finding): measured dur_us carries ~82 us of harness
// workspace-poison fills (2 x 256 MiB fillBuffer @ ~41 us) inside the
// timed graph. The kernel's own residual is ~29 us; target ~18-22 us.
//
// Structure: ONE WAVE = ONE BLOCK = ONE ROW. grid = 2304 = 9 * 256 CUs
// -> perfectly balanced block distribution (the 576-block version left
// 2.25 blocks/CU: 64 CUs ran a 3rd block while 192 idled = 75% util).
// No LDS, no __syncthreads. y register-held (64 VGPR), x streamed with
// 4 independent accumulators, __shfl_xor butterfly, direct store.

#define LL     4096
#define ROWS   (64 * 36)        // 2304 rows = 9 * 256 CUs
#define BLOCK  64               // one wave per block
#define F4LANE (LL / 4 / 64)    // 16 float4 per lane per row

__global__ __launch_bounds__(BLOCK) void spo2_rowscale(
    const float* __restrict__ x,
    const float* __restrict__ y,
    float* __restrict__ out)
{
    const int lane = threadIdx.x;            // 0..63
    const size_t base = (size_t)blockIdx.x * LL;

    const float4* xv = (const float4*)(x + base);
    const float4* yv = (const float4*)(y + base);
    float4*       ov = (float4*)(out + base);

    // y fully register-held: 16 float4 = 64 VGPR.
    float4 yr[F4LANE];
#pragma unroll
    for (int i = 0; i < F4LANE; ++i)
        yr[i] = yv[lane + i * 64];

    // Stream x with 4 independent partial sums (short dep chains).
    float sx0 = 0.f, sx1 = 0.f, sx2 = 0.f, sx3 = 0.f;
#pragma unroll
    for (int i = 0; i < F4LANE; i += 4) {
        float4 a = xv[lane + (i + 0) * 64];
        float4 b = xv[lane + (i + 1) * 64];
        float4 c = xv[lane + (i + 2) * 64];
        float4 d = xv[lane + (i + 3) * 64];
        sx0 += a.x + a.y + a.z + a.w;
        sx1 += b.x + b.y + b.z + b.w;
        sx2 += c.x + c.y + c.z + c.w;
        sx3 += d.x + d.y + d.z + d.w;
    }
    float s = (sx0 + sx1) + (sx2 + sx3);

    // Add y's contribution (already in registers).
    float sy0 = 0.f, sy1 = 0.f;
#pragma unroll
    for (int i = 0; i < F4LANE; i += 2) {
        sy0 += yr[i].x + yr[i].y + yr[i].z + yr[i].w;
        sy1 += yr[i + 1].x + yr[i + 1].y + yr[i + 1].z + yr[i + 1].w;
    }
    s += sy0 + sy1;

    // Wave-64 butterfly: every lane ends with the full row sum.
#pragma unroll
    for (int off = 32; off > 0; off >>= 1)
        s += __shfl_xor(s, off, 64);

    const float scale = s * (1.0f / (float)LL);

#pragma unroll
    for (int i = 0; i < F4LANE; ++i) {
        float4 o;
        o.x = yr[i].x * scale;
        o.y = yr[i].y * scale;
        o.z = yr[i].z * scale;
        o.w = yr[i].w * scale;
        ov[lane + i * 64] = o;
    }
}

extern "C" void kernel_launch(void* const* d_in, const int* in_sizes, int n_in,
                              void* d_out, int out_size, void* d_ws, size_t ws_size,
                              hipStream_t stream) {
    const float* x = (const float*)d_in[0];
    const float* y = (const float*)d_in[1];
    float* out = (float*)d_out;
    spo2_rowscale<<<ROWS, BLOCK, 0, stream>>>(x, y, out);
}

// Round 9
// 107.053 us; speedup vs baseline: 1.0371x; 1.0168x over previous
//
#include <hip/hip_runtime.h>
#include <stdint.h>

// Problem: x0,y0 [B=64, C=36, L=4096] float32.
// out = y0 * (mean(x0,-1) + mean(y0,-1)), float32.
// Memory-bound: 113.2 MB minimal traffic -> ~18 us roofline at 6.3 TB/s.
//
// Harness note: dur_us carries ~82 us of workspace-poison fills
// (2 x 256 MiB fillBuffer @ ~41 us each) inside the timed graph.
// Kernel residual history: 4w/row+barrier (prior session) ~24 us;
// 4 independent waves ~28 us; 1 wave/row (9 waves/CU) ~26 us.
// => occupancy is the lever, NOT barrier avoidance.
//
// This version: one 256-thread block per row (2304 blocks = 36 waves/CU
// requested, 32 resident), __launch_bounds__(256,8) to cap VGPR at 64
// for full 8-waves/SIMD occupancy, all 8 loads issued up front,
// xor-butterfly + tiny LDS combine, nontemporal stores (out is dead
// data for the cache; don't let 37.75 MB of writes thrash L2).

typedef float v4f __attribute__((ext_vector_type(4)));

#define LL    4096
#define ROWS  (64 * 36)         // 2304 blocks, one per (b,c) row
#define BLOCK 256               // 4 waves/row
#define F4T   (LL / 4 / BLOCK)  // 4 float4 per thread

__global__ __launch_bounds__(BLOCK, 8) void spo2_rowscale(
    const float* __restrict__ x,
    const float* __restrict__ y,
    float* __restrict__ out)
{
    const int tid  = threadIdx.x;
    const size_t base = (size_t)blockIdx.x * LL;

    const v4f* xv = (const v4f*)(x + base);
    const v4f* yv = (const v4f*)(y + base);
    v4f*       ov = (v4f*)(out + base);

    // Issue ALL loads before any dependent math (max MLP per wave).
    v4f xr[F4T], yr[F4T];
#pragma unroll
    for (int i = 0; i < F4T; ++i) xr[i] = xv[tid + i * BLOCK];
#pragma unroll
    for (int i = 0; i < F4T; ++i) yr[i] = yv[tid + i * BLOCK];

    // Two independent accumulators.
    float sx = 0.f, sy = 0.f;
#pragma unroll
    for (int i = 0; i < F4T; ++i) {
        sx += xr[i].x + xr[i].y + xr[i].z + xr[i].w;
        sy += yr[i].x + yr[i].y + yr[i].z + yr[i].w;
    }
    float s = sx + sy;

    // Wave-64 xor butterfly: all lanes end with the wave partial.
#pragma unroll
    for (int off = 32; off > 0; off >>= 1)
        s += __shfl_xor(s, off, 64);

    // Cross-wave combine: 4 floats in LDS, one barrier, broadcast reads.
    __shared__ float rs[BLOCK / 64];
    const int wid  = tid >> 6;
    const int lane = tid & 63;
    if (lane == 0) rs[wid] = s;
    __syncthreads();

    float total = 0.f;
#pragma unroll
    for (int w = 0; w < BLOCK / 64; ++w) total += rs[w];
    const float scale = total * (1.0f / (float)LL);

    // Nontemporal stores: out is never re-read, skip L2 allocation.
#pragma unroll
    for (int i = 0; i < F4T; ++i) {
        v4f o = yr[i] * scale;
        __builtin_nontemporal_store(o, ov + tid + i * BLOCK);
    }
}

extern "C" void kernel_launch(void* const* d_in, const int* in_sizes, int n_in,
                              void* d_out, int out_size, void* d_ws, size_t ws_size,
                              hipStream_t stream) {
    const float* x = (const float*)d_in[0];
    const float* y = (const float*)d_in[1];
    float* out = (float*)d_out;
    spo2_rowscale<<<ROWS, BLOCK, 0, stream>>>(x, y, out);
}